// Round 12
// baseline (23.384 us; speedup 1.0000x reference)
//
#include <hip/hip_runtime.h>
#include <hip/hip_bf16.h>

// MSAColumnAttention fused MFMA kernel for MI355X (gfx950).
// S=64, I=128, C=64, D=32, H=8, F=256.
// R12: kill the per-block strided W gathers (the invisible ~10us L1-pipe
// serialization): a prep kernel gathers W ONCE into d_ws as bf16 fragments in
// exact MFMA lane order (q-scale folded). Main kernel (R8 body) then does 8
// coalesced dwordx4 fragment loads instead of 64 scattered dword gathers.
// Dispatches: w_prep -> main (grid 512 = i x fq, 512 thr, register-resident
// poly-softmax attention) -> reduce4 (launch overhead measured ~0).

#define TPB 512

typedef __attribute__((ext_vector_type(8))) short bf16x8;
typedef __attribute__((ext_vector_type(4))) float f32x4;

__device__ __forceinline__ unsigned short f2bf(float f) {
    __hip_bfloat16 h = __float2bfloat16(f);           // RNE
    return *reinterpret_cast<unsigned short*>(&h);
}
__device__ __forceinline__ bf16x8 pack8(const float* t) {
    union { unsigned short u[8]; bf16x8 v8; } pk;
    #pragma unroll
    for (int j = 0; j < 8; ++j) pk.u[j] = f2bf(t[j]);
    return pk.v8;
}

// ---- W prep: gather fp32 W -> bf16 fragments in MFMA lane order ----
// wpk chunks of 8 u16 (16B): id 0..8191 = WB[fq][wv][nn][kt][l] (QKVG),
// id 8192..10239 = OF[fq][nh2][nn][kt][l] (Wout). Per chunk j=0..7 k-rows.
__global__ __launch_bounds__(256) void w_prep(
    const float* __restrict__ Wqkv,  // [64,768]
    const float* __restrict__ Wg,    // [64,256]
    const float* __restrict__ Wout,  // [256,64]
    unsigned short* __restrict__ wpk)
{
    const int id = blockIdx.x * 256 + threadIdx.x;   // 0..10239
    const int l    = id & 63;
    const int lo16 = l & 15;
    const int rloc = (l >> 4) * 8;                   // lg*8
    unsigned short outv[8];
    if (id < 8192) {
        const int kt = (id >> 6) & 1;
        const int nn = (id >> 7) & 1;
        const int wv = (id >> 8) & 7;
        const int fq = id >> 11;
        const int f  = fq * 64 + wv * 8 + (lo16 & 7);
        const bool qlo = lo16 < 8;
        const float scale = (nn == 0 && qlo) ? 0.17677670f : 1.0f;  // 1/sqrt(32) into q
        #pragma unroll
        for (int j = 0; j < 8; ++j) {
            const int r = kt * 32 + rloc + j;
            float v;
            if (nn == 0) v = Wqkv[r * 768 + (qlo ? f : 256 + f)];          // q | k
            else         v = qlo ? Wqkv[r * 768 + 512 + f] : Wg[r * 256 + f]; // v | g
            outv[j] = f2bf(v * scale);
        }
    } else {
        const int id2 = id - 8192;
        const int kt  = (id2 >> 6) & 1;
        const int nn  = (id2 >> 7) & 1;
        const int nh2 = (id2 >> 8) & 1;
        const int fq  = id2 >> 9;
        const int c   = (nh2 * 2 + nn) * 16 + lo16;
        #pragma unroll
        for (int j = 0; j < 8; ++j)
            outv[j] = f2bf(Wout[(fq * 64 + kt * 32 + rloc + j) * 64 + c]);
    }
    *(bf16x8*)(wpk + (size_t)id * 8) = *(const bf16x8*)outv;
}

__global__ __launch_bounds__(TPB, 2) void msa_col_attn_mfma(
    const float* __restrict__ msa,   // [64,128,64]
    const float* __restrict__ ln_s,  // [64]
    const float* __restrict__ ln_b,  // [64]
    const unsigned short* __restrict__ wpk,  // packed W fragments
    float* __restrict__ Pws)         // [4 fq][64 s][128 i][64 c] partials
{
    // XF: X A-frags 8192B | XFo: attn-out A-frags 8192B.
    __shared__ __align__(16) char smem[8192 + 8192];
    unsigned short* XF  = (unsigned short*)smem;
    unsigned short* XFo = (unsigned short*)(smem + 8192);

    const int tid  = threadIdx.x;
    const int i    = blockIdx.x >> 2;
    const int fq   = blockIdx.x & 3;
    const int l    = tid & 63;
    const int wv   = tid >> 6;     // wave id 0..7 (uniform)
    const int lg   = l >> 4;
    const int ln16 = l & 15;
    const bool lo  = ln16 < 8;
    const int mt4  = wv & 3, nh2 = wv >> 2;

    // ---- coalesced fragment loads (replace all W gathers) ----
    bf16x8 bfr[2][2];   // [nn][kt] QKVG B-frags (q-scale pre-folded)
    #pragma unroll
    for (int nn = 0; nn < 2; ++nn)
        #pragma unroll
        for (int kt = 0; kt < 2; ++kt)
            bfr[nn][kt] = *(const bf16x8*)(wpk +
                (size_t)(((fq << 11) | (wv << 8) | (nn << 7) | (kt << 6) | l)) * 8);
    bf16x8 ofr[2][2];   // [nn][kt] Wout B-frags
    #pragma unroll
    for (int nn = 0; nn < 2; ++nn)
        #pragma unroll
        for (int kt = 0; kt < 2; ++kt)
            ofr[nn][kt] = *(const bf16x8*)(wpk +
                (size_t)(8192 + ((fq << 9) | (nh2 << 8) | (nn << 7) | (kt << 6) | l)) * 8);

    // ---- msa loads ----
    const int sL = tid >> 3;
    const int c0 = (tid & 7) * 8;
    const float* rowp = msa + (sL * 128 + i) * 64 + c0;
    const float4 m0 = *(const float4*)(rowp);
    const float4 m1 = *(const float4*)(rowp + 4);

    // ---------------- LayerNorm -> X A-fragments ----------------
    {
        float v[8] = {m0.x, m0.y, m0.z, m0.w, m1.x, m1.y, m1.z, m1.w};
        float sum = 0.f, sq = 0.f;
        #pragma unroll
        for (int j = 0; j < 8; ++j) { sum += v[j]; sq += v[j] * v[j]; }
        sum += __shfl_xor(sum, 1);  sq += __shfl_xor(sq, 1);
        sum += __shfl_xor(sum, 2);  sq += __shfl_xor(sq, 2);
        sum += __shfl_xor(sum, 4);  sq += __shfl_xor(sq, 4);
        const float mu  = sum * (1.f / 64.f);
        const float var = sq * (1.f / 64.f) - mu * mu;
        const float rs  = __builtin_amdgcn_rsqf(var + 1e-5f);
        const float4 s0 = *(const float4*)(ln_s + c0);
        const float4 s1 = *(const float4*)(ln_s + c0 + 4);
        const float4 b0 = *(const float4*)(ln_b + c0);
        const float4 b1 = *(const float4*)(ln_b + c0 + 4);
        const float sc[8] = {s0.x,s0.y,s0.z,s0.w,s1.x,s1.y,s1.z,s1.w};
        const float bi[8] = {b0.x,b0.y,b0.z,b0.w,b1.x,b1.y,b1.z,b1.w};
        float t[8];
        #pragma unroll
        for (int j = 0; j < 8; ++j) t[j] = (v[j] - mu) * rs * sc[j] + bi[j];
        const int kt = c0 >> 5, g = (c0 >> 3) & 3, mt = sL >> 4;
        *(bf16x8*)(XF + (((kt * 4 + mt) * 64) + g * 16 + (sL & 15)) * 8) = pack8(t);
    }
    __syncthreads();

    // ---------------- QKVG MFMA: acc[mt][0] = q|k, acc[mt][1] = v|g ----------
    f32x4 acc[4][2];
    #pragma unroll
    for (int mt = 0; mt < 4; ++mt)
        #pragma unroll
        for (int nn = 0; nn < 2; ++nn) acc[mt][nn] = (f32x4){0.f, 0.f, 0.f, 0.f};
    #pragma unroll
    for (int kt = 0; kt < 2; ++kt)
        #pragma unroll
        for (int mt = 0; mt < 4; ++mt) {
            const bf16x8 a = *(const bf16x8*)(XF + ((kt * 4 + mt) * 64 + l) * 8);
            #pragma unroll
            for (int nn = 0; nn < 2; ++nn)
                acc[mt][nn] = __builtin_amdgcn_mfma_f32_16x16x32_bf16(
                    a, bfr[nn][kt], acc[mt][nn], 0, 0, 0);
        }

    // ---------------- register-resident attention ----------------
    // shfl_xor(8) on acc[.][0]: low lanes receive k (pair with local v),
    // high lanes receive q (pair with local g). Rows = t = mt*16 + lg*4 + r;
    // butterfly over lg = xor16, xor32.
    {
        float kq[4][4];
        #pragma unroll
        for (int mt = 0; mt < 4; ++mt)
            #pragma unroll
            for (int r = 0; r < 4; ++r)
                kq[mt][r] = __shfl_xor(acc[mt][0][r], 8);

        float L1 = 0.f, L2 = 0.f, L3 = 0.f, L4 = 0.f;
        float M0 = 0.f, M1 = 0.f, M2 = 0.f, M3 = 0.f, M4 = 0.f;
        #pragma unroll
        for (int mt = 0; mt < 4; ++mt)
            #pragma unroll
            for (int r = 0; r < 4; ++r) {
                const float k1 = kq[mt][r];          // low: k_t
                const float vv = acc[mt][1][r];      // low: v_t
                const float k2 = k1 * k1;
                const float k3 = k2 * k1;
                const float k4 = k2 * k2;
                L1 += k1; L2 += k2; L3 += k3; L4 += k4;
                M0 += vv;
                M1 = fmaf(k1, vv, M1);
                M2 = fmaf(k2, vv, M2);
                M3 = fmaf(k3, vv, M3);
                M4 = fmaf(k4, vv, M4);
            }
        #pragma unroll
        for (int m = 16; m <= 32; m <<= 1) {
            L1 += __shfl_xor(L1, m); L2 += __shfl_xor(L2, m);
            L3 += __shfl_xor(L3, m); L4 += __shfl_xor(L4, m);
            M0 += __shfl_xor(M0, m); M1 += __shfl_xor(M1, m);
            M2 += __shfl_xor(M2, m); M3 += __shfl_xor(M3, m);
            M4 += __shfl_xor(M4, m);
        }
        // broadcast low-half moments to high half
        L1 = __shfl_xor(L1, 8); L2 = __shfl_xor(L2, 8);
        L3 = __shfl_xor(L3, 8); L4 = __shfl_xor(L4, 8);
        M0 = __shfl_xor(M0, 8); M1 = __shfl_xor(M1, 8);
        M2 = __shfl_xor(M2, 8); M3 = __shfl_xor(M3, 8);
        M4 = __shfl_xor(M4, 8);

        // sigmoid of local g (meaningful on high lanes)
        float gs[4][4];
        #pragma unroll
        for (int mt = 0; mt < 4; ++mt)
            #pragma unroll
            for (int r = 0; r < 4; ++r)
                gs[mt][r] = __builtin_amdgcn_rcpf(
                    1.f + __builtin_amdgcn_exp2f(acc[mt][1][r] * -1.44269504f));

        if (!lo) {
            const float a4 = L4 * (1.f / 24.f), a3 = L3 * (1.f / 6.f), a2 = L2 * 0.5f;
            const float b4 = M4 * (1.f / 24.f), b3 = M3 * (1.f / 6.f), b2 = M2 * 0.5f;
            const int kt2 = wv >> 2, g2 = wv & 3, jj = ln16 - 8;
            #pragma unroll
            for (int mt = 0; mt < 4; ++mt)
                #pragma unroll
                for (int r = 0; r < 4; ++r) {
                    const float qv = kq[mt][r];
                    const float den = fmaf(fmaf(fmaf(fmaf(a4, qv, a3), qv, a2), qv, L1), qv, 64.f);
                    const float num = fmaf(fmaf(fmaf(fmaf(b4, qv, b3), qv, b2), qv, M1), qv, M0);
                    const float o   = gs[mt][r] * num * __builtin_amdgcn_rcpf(den);
                    XFo[((kt2 * 4 + mt) * 64 + g2 * 16 + lg * 4 + r) * 8 + jj] = f2bf(o);
                }
        }
    }
    __syncthreads();

    // ---------------- out-proj via MFMA -> partial store ----------------
    // wave -> (mt4 s-block, nh2 c-half). M=64 s, N=64 c, K=64 f-local.
    {
        bf16x8 afr[2];
        #pragma unroll
        for (int kt = 0; kt < 2; ++kt)
            afr[kt] = *(const bf16x8*)(XFo + ((kt * 4 + mt4) * 64 + l) * 8);
        #pragma unroll
        for (int nn = 0; nn < 2; ++nn) {
            const int cc = (nh2 * 2 + nn) * 16 + ln16;
            f32x4 a2 = (f32x4){0.f, 0.f, 0.f, 0.f};
            #pragma unroll
            for (int kt = 0; kt < 2; ++kt)
                a2 = __builtin_amdgcn_mfma_f32_16x16x32_bf16(afr[kt], ofr[nn][kt], a2, 0, 0, 0);
            #pragma unroll
            for (int r = 0; r < 4; ++r) {
                const int s = mt4 * 16 + lg * 4 + r;
                Pws[((fq * 64 + s) * 128 + i) * 64 + cc] = a2[r];
            }
        }
    }
}

// out = P0+P1+P2+P3 + bias; 131072 float4's over 256 blocks x 512 threads.
__global__ __launch_bounds__(512) void reduce4(
    const float* __restrict__ P, const float* __restrict__ bout,
    float* __restrict__ out)
{
    const int e = (blockIdx.x * 512 + threadIdx.x) * 4;
    const float4 a = *(const float4*)(P + e);
    const float4 b = *(const float4*)(P + 524288 + e);
    const float4 c = *(const float4*)(P + 2 * 524288 + e);
    const float4 d = *(const float4*)(P + 3 * 524288 + e);
    const float4 bb = *(const float4*)(bout + (e & 63));
    float4 r;
    r.x = a.x + b.x + c.x + d.x + bb.x;
    r.y = a.y + b.y + c.y + d.y + bb.y;
    r.z = a.z + b.z + c.z + d.z + bb.z;
    r.w = a.w + b.w + c.w + d.w + bb.w;
    *(float4*)(out + e) = r;
}

extern "C" void kernel_launch(void* const* d_in, const int* in_sizes, int n_in,
                              void* d_out, int out_size, void* d_ws, size_t ws_size,
                              hipStream_t stream) {
    (void)in_sizes; (void)n_in; (void)ws_size; (void)out_size;
    const float* msa  = (const float*)d_in[0];
    const float* ln_s = (const float*)d_in[1];
    const float* ln_b = (const float*)d_in[2];
    const float* Wqkv = (const float*)d_in[3];
    const float* Wg   = (const float*)d_in[4];
    const float* Wout = (const float*)d_in[5];
    const float* bout = (const float*)d_in[6];
    float* out = (float*)d_out;
    float* Pws = (float*)d_ws;                         // 8 MB of partials
    unsigned short* wpk = (unsigned short*)(Pws + 4 * 524288);  // +160 KB packed W

    w_prep<<<dim3(40), dim3(256), 0, stream>>>(Wqkv, Wg, Wout, wpk);
    msa_col_attn_mfma<<<dim3(512), dim3(TPB), 0, stream>>>(
        msa, ln_s, ln_b, wpk, Pws);
    reduce4<<<dim3(256), dim3(512), 0, stream>>>(Pws, bout, out);
}

// Round 13
// 18.977 us; speedup vs baseline: 1.2322x; 1.2322x over previous
//
#include <hip/hip_runtime.h>
#include <hip/hip_bf16.h>

// MSAColumnAttention fused MFMA kernel for MI355X (gfx950).
// S=64, I=128, C=64, D=32, H=8, F=256.
// R13: cold-cache model (harness re-poisons 268MB d_ws between replays ->
// L2/L3 flushed every replay). Minimize cold-HBM bytes, all streaming:
//   wprep: pack W once -> 256KB bf16 MFMA fragments (q-scale folded).
//   main: grid 128 (one block per residue i) x 1024 thr (16 waves x 16
//   features): msa fetched exactly once (2MB), QKVG MFMA (4 sec accs/lane,
//   all lanes useful), in-register poly-softmax (moments + xor16/32
//   butterfly only), out-proj K=256 in-block -> DIRECT out store + bias.
// No Pws round-trip, no reduce kernel, no atomics, no memset. 2 dispatches.

typedef __attribute__((ext_vector_type(8))) short bf16x8;
typedef __attribute__((ext_vector_type(4))) float f32x4;

__device__ __forceinline__ unsigned short f2bf(float f) {
    __hip_bfloat16 h = __float2bfloat16(f);           // RNE
    return *reinterpret_cast<unsigned short*>(&h);
}
__device__ __forceinline__ bf16x8 pack8(const float* t) {
    union { unsigned short u[8]; bf16x8 v8; } pk;
    #pragma unroll
    for (int j = 0; j < 8; ++j) pk.u[j] = f2bf(t[j]);
    return pk.v8;
}

// ---- W prep: gather fp32 W -> bf16 fragments in MFMA lane order ----
// 16B chunks. id 0..8191:  QKVG  chunk = w*512 + sec*128 + kt*64 + l
//   (w=wave 0..15 -> features w*16+ln16; sec in {q,k,v,g}; kt k-tile; l lane)
// id 8192..16383: Wout chunk = 8192 + w*512 + kt*64 + l
//   (w: nn2=w>>2 -> c = nn2*16+ln16; kt 0..7 k-tiles of 32)
__global__ __launch_bounds__(256) void w_prep(
    const float* __restrict__ Wqkv,  // [64,768]
    const float* __restrict__ Wg,    // [64,256]
    const float* __restrict__ Wout,  // [256,64]
    unsigned short* __restrict__ wpk)
{
    const int id = blockIdx.x * 256 + threadIdx.x;   // 0..16383
    const int l    = id & 63;
    const int ln16 = l & 15;
    const int rloc = (l >> 4) * 8;                   // lg*8
    unsigned short outv[8];
    if (id < 8192) {
        const int kt  = (id >> 6) & 1;
        const int sec = (id >> 7) & 3;
        const int w   = id >> 9;
        const int f   = w * 16 + ln16;
        const float scale = (sec == 0) ? 0.17677670f : 1.0f;   // 1/sqrt(32) into q
        #pragma unroll
        for (int j = 0; j < 8; ++j) {
            const int r = kt * 32 + rloc + j;
            float v;
            if (sec == 3) v = Wg[r * 256 + f];
            else          v = Wqkv[r * 768 + sec * 256 + f];
            outv[j] = f2bf(v * scale);
        }
    } else {
        const int id2 = id - 8192;
        const int kt  = (id2 >> 6) & 7;
        const int w   = id2 >> 9;
        const int cc  = (w >> 2) * 16 + ln16;
        #pragma unroll
        for (int j = 0; j < 8; ++j)
            outv[j] = f2bf(Wout[(kt * 32 + rloc + j) * 64 + cc]);
    }
    *(bf16x8*)(wpk + (size_t)id * 8) = *(const bf16x8*)outv;
}

__global__ __launch_bounds__(1024, 1) void msa_col_attn_mfma(
    const float* __restrict__ msa,   // [64,128,64]
    const float* __restrict__ ln_s,  // [64]
    const float* __restrict__ ln_b,  // [64]
    const unsigned short* __restrict__ wpk,  // packed W fragments
    const float* __restrict__ bout,  // [64]
    float* __restrict__ out)         // [64,128,64]
{
    // XF: X A-frags [2kt][4mt][64][8] = 8192B.
    // XFo: attn-out A-frags [8kt][4mt][64][8] = 32768B (K=256).
    __shared__ __align__(16) char smem[8192 + 32768];
    unsigned short* XF  = (unsigned short*)smem;
    unsigned short* XFo = (unsigned short*)(smem + 8192);

    const int tid  = threadIdx.x;
    const int i    = blockIdx.x;     // residue
    const int l    = tid & 63;
    const int wv   = tid >> 6;       // wave id 0..15 (uniform)
    const int lg   = l >> 4;
    const int ln16 = l & 15;

    // ---- all waves: issue coalesced QKVG fragment loads ----
    bf16x8 bfr[4][2];   // [sec][kt], features wv*16+ln16
    #pragma unroll
    for (int sec = 0; sec < 4; ++sec)
        #pragma unroll
        for (int kt = 0; kt < 2; ++kt)
            bfr[sec][kt] = *(const bf16x8*)(wpk +
                (size_t)(wv * 512 + sec * 128 + kt * 64 + l) * 8);

    // ---- waves 0-7: msa load + LayerNorm -> X A-fragments ----
    if (wv < 8) {
        const int sL = tid >> 3;          // s row (tid < 512)
        const int c0 = (tid & 7) * 8;
        const float* rowp = msa + (sL * 128 + i) * 64 + c0;
        const float4 m0 = *(const float4*)(rowp);
        const float4 m1 = *(const float4*)(rowp + 4);
        float v[8] = {m0.x, m0.y, m0.z, m0.w, m1.x, m1.y, m1.z, m1.w};
        float sum = 0.f, sq = 0.f;
        #pragma unroll
        for (int j = 0; j < 8; ++j) { sum += v[j]; sq += v[j] * v[j]; }
        sum += __shfl_xor(sum, 1);  sq += __shfl_xor(sq, 1);
        sum += __shfl_xor(sum, 2);  sq += __shfl_xor(sq, 2);
        sum += __shfl_xor(sum, 4);  sq += __shfl_xor(sq, 4);
        const float mu  = sum * (1.f / 64.f);
        const float var = sq * (1.f / 64.f) - mu * mu;
        const float rs  = __builtin_amdgcn_rsqf(var + 1e-5f);
        const float4 s0 = *(const float4*)(ln_s + c0);
        const float4 s1 = *(const float4*)(ln_s + c0 + 4);
        const float4 b0 = *(const float4*)(ln_b + c0);
        const float4 b1 = *(const float4*)(ln_b + c0 + 4);
        const float sc[8] = {s0.x,s0.y,s0.z,s0.w,s1.x,s1.y,s1.z,s1.w};
        const float bi[8] = {b0.x,b0.y,b0.z,b0.w,b1.x,b1.y,b1.z,b1.w};
        float t[8];
        #pragma unroll
        for (int j = 0; j < 8; ++j) t[j] = (v[j] - mu) * rs * sc[j] + bi[j];
        const int kt = c0 >> 5, g = (c0 >> 3) & 3, mt = sL >> 4;
        *(bf16x8*)(XF + (((kt * 4 + mt) * 64) + g * 16 + (sL & 15)) * 8) = pack8(t);
    }
    __syncthreads();

    // ---------------- QKVG MFMA: acc[mt][sec], rows = x-row (s or t) --------
    f32x4 acc[4][4];
    #pragma unroll
    for (int mt = 0; mt < 4; ++mt)
        #pragma unroll
        for (int sec = 0; sec < 4; ++sec) acc[mt][sec] = (f32x4){0.f, 0.f, 0.f, 0.f};
    #pragma unroll
    for (int kt = 0; kt < 2; ++kt)
        #pragma unroll
        for (int mt = 0; mt < 4; ++mt) {
            const bf16x8 a = *(const bf16x8*)(XF + ((kt * 4 + mt) * 64 + l) * 8);
            #pragma unroll
            for (int sec = 0; sec < 4; ++sec)
                acc[mt][sec] = __builtin_amdgcn_mfma_f32_16x16x32_bf16(
                    a, bfr[sec][kt], acc[mt][sec], 0, 0, 0);
        }

    // ---------------- register-resident attention (all lanes useful) --------
    // lane's feature f = wv*16 + ln16. acc rows: idx = mt*16 + lg*4 + r.
    // k = acc[.][1], v = acc[.][2] -> 16 t-partials; butterfly xor16/32 sums
    // all 64 t. q = acc[.][0] (pre-scaled), g = acc[.][3] -> 16 s outputs.
    {
        float L1 = 0.f, L2 = 0.f, L3 = 0.f, L4 = 0.f;
        float M0 = 0.f, M1 = 0.f, M2 = 0.f, M3 = 0.f, M4 = 0.f;
        #pragma unroll
        for (int mt = 0; mt < 4; ++mt)
            #pragma unroll
            for (int r = 0; r < 4; ++r) {
                const float k1 = acc[mt][1][r];
                const float vv = acc[mt][2][r];
                const float k2 = k1 * k1;
                const float k3 = k2 * k1;
                const float k4 = k2 * k2;
                L1 += k1; L2 += k2; L3 += k3; L4 += k4;
                M0 += vv;
                M1 = fmaf(k1, vv, M1);
                M2 = fmaf(k2, vv, M2);
                M3 = fmaf(k3, vv, M3);
                M4 = fmaf(k4, vv, M4);
            }
        #pragma unroll
        for (int m = 16; m <= 32; m <<= 1) {
            L1 += __shfl_xor(L1, m); L2 += __shfl_xor(L2, m);
            L3 += __shfl_xor(L3, m); L4 += __shfl_xor(L4, m);
            M0 += __shfl_xor(M0, m); M1 += __shfl_xor(M1, m);
            M2 += __shfl_xor(M2, m); M3 += __shfl_xor(M3, m);
            M4 += __shfl_xor(M4, m);
        }
        const float a4 = L4 * (1.f / 24.f), a3 = L3 * (1.f / 6.f), a2 = L2 * 0.5f;
        const float b4 = M4 * (1.f / 24.f), b3 = M3 * (1.f / 6.f), b2 = M2 * 0.5f;

        // XFo A-frag coords for feature f: kt2 = wv>>1, g2 = (wv&1)*2 + (ln16>>3),
        // jj = ln16&7  (f = kt2*32 + g2*8 + jj = wv*16 + ln16).
        const int kt2 = wv >> 1;
        const int g2  = (wv & 1) * 2 + (ln16 >> 3);
        const int jj  = ln16 & 7;
        #pragma unroll
        for (int mt = 0; mt < 4; ++mt)
            #pragma unroll
            for (int r = 0; r < 4; ++r) {
                const float qv = acc[mt][0][r];
                const float gv = __builtin_amdgcn_rcpf(
                    1.f + __builtin_amdgcn_exp2f(acc[mt][3][r] * -1.44269504f));
                const float den = fmaf(fmaf(fmaf(fmaf(a4, qv, a3), qv, a2), qv, L1), qv, 64.f);
                const float num = fmaf(fmaf(fmaf(fmaf(b4, qv, b3), qv, b2), qv, M1), qv, M0);
                const float o   = gv * num * __builtin_amdgcn_rcpf(den);
                XFo[((kt2 * 4 + mt) * 64 + g2 * 16 + lg * 4 + r) * 8 + jj] = f2bf(o);
            }
    }
    __syncthreads();

    // ---------------- out-proj (K=256) -> direct store + bias ----------------
    // wave -> (mt = wv&3 s-block, nn2 = wv>>2 c-tile of 16). 8 kt MFMAs.
    {
        const int mt  = wv & 3;
        const int nn2 = wv >> 2;
        const int cc  = nn2 * 16 + ln16;
        f32x4 a2v = (f32x4){0.f, 0.f, 0.f, 0.f};
        #pragma unroll
        for (int kt = 0; kt < 8; ++kt) {
            const bf16x8 afr = *(const bf16x8*)(XFo + ((kt * 4 + mt) * 64 + l) * 8);
            const bf16x8 ofr = *(const bf16x8*)(wpk +
                (size_t)(8192 + wv * 512 + kt * 64 + l) * 8);
            a2v = __builtin_amdgcn_mfma_f32_16x16x32_bf16(afr, ofr, a2v, 0, 0, 0);
        }
        const float bb = bout[cc];
        #pragma unroll
        for (int r = 0; r < 4; ++r) {
            const int s = mt * 16 + lg * 4 + r;
            out[(s * 128 + i) * 64 + cc] = a2v[r] + bb;
        }
    }
}

extern "C" void kernel_launch(void* const* d_in, const int* in_sizes, int n_in,
                              void* d_out, int out_size, void* d_ws, size_t ws_size,
                              hipStream_t stream) {
    (void)in_sizes; (void)n_in; (void)ws_size; (void)out_size;
    const float* msa  = (const float*)d_in[0];
    const float* ln_s = (const float*)d_in[1];
    const float* ln_b = (const float*)d_in[2];
    const float* Wqkv = (const float*)d_in[3];
    const float* Wg   = (const float*)d_in[4];
    const float* Wout = (const float*)d_in[5];
    const float* bout = (const float*)d_in[6];
    float* out = (float*)d_out;
    unsigned short* wpk = (unsigned short*)d_ws;   // 256 KB packed W

    w_prep<<<dim3(64), dim3(256), 0, stream>>>(Wqkv, Wg, Wout, wpk);
    msa_col_attn_mfma<<<dim3(128), dim3(1024), 0, stream>>>(
        msa, ln_s, ln_b, wpk, bout, out);
}

// Round 14
// 16.118 us; speedup vs baseline: 1.4508x; 1.1774x over previous
//
#include <hip/hip_runtime.h>
#include <hip/hip_bf16.h>

// MSAColumnAttention fully-fused SINGLE-dispatch kernel for MI355X (gfx950).
// S=64, I=128, C=64, D=32, H=8, F=256. Grid 128 = one block per residue i,
// 1024 thr (16 waves x 16 features). R14 = R13 body with the W-prep folded in
// as per-block register gathers (R8-style, proven ~free when overlapped):
//   - 64 scattered QKVG W dwords issued BEFORE LN (hide under msa+LN+barrier)
//   - QKVG MFMA: acc[mt][sec] for sec in {q,k,v,g} (all lanes useful)
//   - 64 Wout dwords issued after QKVG MFMA (hide under attention)
//   - in-register poly-softmax: moments L_n,M_n + xor16/32 butterfly, Horner
//   - out-proj K=256 in-block -> DIRECT store + bias.
// No d_ws, no second dispatch, no atomics, no memset.

typedef __attribute__((ext_vector_type(8))) short bf16x8;
typedef __attribute__((ext_vector_type(4))) float f32x4;

__device__ __forceinline__ unsigned short f2bf(float f) {
    __hip_bfloat16 h = __float2bfloat16(f);           // RNE
    return *reinterpret_cast<unsigned short*>(&h);
}
__device__ __forceinline__ bf16x8 pack8(const float* t) {
    union { unsigned short u[8]; bf16x8 v8; } pk;
    #pragma unroll
    for (int j = 0; j < 8; ++j) pk.u[j] = f2bf(t[j]);
    return pk.v8;
}

__global__ __launch_bounds__(1024, 1) void msa_col_attn_fused(
    const float* __restrict__ msa,   // [64,128,64]
    const float* __restrict__ ln_s,  // [64]
    const float* __restrict__ ln_b,  // [64]
    const float* __restrict__ Wqkv,  // [64,768]
    const float* __restrict__ Wg,    // [64,256]
    const float* __restrict__ Wout,  // [256,64]
    const float* __restrict__ bout,  // [64]
    float* __restrict__ out)         // [64,128,64]
{
    // XF: X A-frags [2kt][4mt][64][8] = 8192B.
    // XFo: attn-out A-frags [8kt][4mt][64][8] = 32768B (K=256).
    __shared__ __align__(16) char smem[8192 + 32768];
    unsigned short* XF  = (unsigned short*)smem;
    unsigned short* XFo = (unsigned short*)(smem + 8192);

    const int tid  = threadIdx.x;
    const int i    = blockIdx.x;     // residue
    const int l    = tid & 63;
    const int wv   = tid >> 6;       // wave id 0..15 (uniform)
    const int lg   = l >> 4;
    const int ln16 = l & 15;
    const int f    = wv * 16 + ln16; // this lane's feature (QKVG phase)

    // ---- issue msa loads first (waves 0-7 consume in LN) ----
    const int sL = tid >> 3;
    const int c0 = (tid & 7) * 8;
    const float* rowp = msa + ((sL & 63) * 128 + i) * 64 + c0;
    float4 m0, m1;
    if (wv < 8) { m0 = *(const float4*)(rowp); m1 = *(const float4*)(rowp + 4); }

    // ---- issue QKVG W gathers (latency hides under msa+LN+barrier) ----
    float wqg[4][2][8];   // [sec][kt][j]
    #pragma unroll
    for (int sec = 0; sec < 4; ++sec)
        #pragma unroll
        for (int kt = 0; kt < 2; ++kt)
            #pragma unroll
            for (int j = 0; j < 8; ++j) {
                const int r = kt * 32 + lg * 8 + j;
                wqg[sec][kt][j] = (sec == 3) ? Wg[r * 256 + f]
                                             : Wqkv[r * 768 + sec * 256 + f];
            }

    // ---- waves 0-7: LayerNorm -> X A-fragments ----
    if (wv < 8) {
        float v[8] = {m0.x, m0.y, m0.z, m0.w, m1.x, m1.y, m1.z, m1.w};
        float sum = 0.f, sq = 0.f;
        #pragma unroll
        for (int j = 0; j < 8; ++j) { sum += v[j]; sq += v[j] * v[j]; }
        sum += __shfl_xor(sum, 1);  sq += __shfl_xor(sq, 1);
        sum += __shfl_xor(sum, 2);  sq += __shfl_xor(sq, 2);
        sum += __shfl_xor(sum, 4);  sq += __shfl_xor(sq, 4);
        const float mu  = sum * (1.f / 64.f);
        const float var = sq * (1.f / 64.f) - mu * mu;
        const float rs  = __builtin_amdgcn_rsqf(var + 1e-5f);
        const float4 s0 = *(const float4*)(ln_s + c0);
        const float4 s1 = *(const float4*)(ln_s + c0 + 4);
        const float4 b0 = *(const float4*)(ln_b + c0);
        const float4 b1 = *(const float4*)(ln_b + c0 + 4);
        const float sc[8] = {s0.x,s0.y,s0.z,s0.w,s1.x,s1.y,s1.z,s1.w};
        const float bi[8] = {b0.x,b0.y,b0.z,b0.w,b1.x,b1.y,b1.z,b1.w};
        float t[8];
        #pragma unroll
        for (int j = 0; j < 8; ++j) t[j] = (v[j] - mu) * rs * sc[j] + bi[j];
        const int kt = c0 >> 5, g = (c0 >> 3) & 3, mt = sL >> 4;
        *(bf16x8*)(XF + (((kt * 4 + mt) * 64) + g * 16 + (sL & 15)) * 8) = pack8(t);
    }

    // pack QKVG W frags (q-scale folded) while LN finishes
    bf16x8 bfr[4][2];   // [sec][kt]
    #pragma unroll
    for (int kt = 0; kt < 2; ++kt) {
        float t0[8];
        #pragma unroll
        for (int j = 0; j < 8; ++j) t0[j] = wqg[0][kt][j] * 0.17677670f;  // 1/sqrt(32)
        bfr[0][kt] = pack8(t0);
        bfr[1][kt] = pack8(wqg[1][kt]);
        bfr[2][kt] = pack8(wqg[2][kt]);
        bfr[3][kt] = pack8(wqg[3][kt]);
    }
    __syncthreads();

    // ---------------- QKVG MFMA: acc[mt][sec], rows = x-row (s or t) --------
    f32x4 acc[4][4];
    #pragma unroll
    for (int mt = 0; mt < 4; ++mt)
        #pragma unroll
        for (int sec = 0; sec < 4; ++sec) acc[mt][sec] = (f32x4){0.f, 0.f, 0.f, 0.f};
    #pragma unroll
    for (int kt = 0; kt < 2; ++kt)
        #pragma unroll
        for (int mt = 0; mt < 4; ++mt) {
            const bf16x8 a = *(const bf16x8*)(XF + ((kt * 4 + mt) * 64 + l) * 8);
            #pragma unroll
            for (int sec = 0; sec < 4; ++sec)
                acc[mt][sec] = __builtin_amdgcn_mfma_f32_16x16x32_bf16(
                    a, bfr[sec][kt], acc[mt][sec], 0, 0, 0);
        }

    // ---- issue Wout gathers now; latency hides under attention ----
    const int mt4 = wv & 3, nn2 = wv >> 2;
    const int cc  = nn2 * 16 + ln16;
    float wo[8][8];   // [kt][j]
    #pragma unroll
    for (int kt = 0; kt < 8; ++kt)
        #pragma unroll
        for (int j = 0; j < 8; ++j)
            wo[kt][j] = Wout[(kt * 32 + lg * 8 + j) * 64 + cc];

    // ---------------- register-resident attention (all lanes useful) --------
    // lane's feature f. acc rows: idx = mt*16 + lg*4 + r.
    // k = acc[.][1], v = acc[.][2] -> 16 t-partials; xor16/32 butterfly sums
    // all 64 t. q = acc[.][0] (pre-scaled), g = acc[.][3] -> 16 s outputs.
    {
        float L1 = 0.f, L2 = 0.f, L3 = 0.f, L4 = 0.f;
        float M0 = 0.f, M1 = 0.f, M2 = 0.f, M3 = 0.f, M4 = 0.f;
        #pragma unroll
        for (int mt = 0; mt < 4; ++mt)
            #pragma unroll
            for (int r = 0; r < 4; ++r) {
                const float k1 = acc[mt][1][r];
                const float vv = acc[mt][2][r];
                const float k2 = k1 * k1;
                const float k3 = k2 * k1;
                const float k4 = k2 * k2;
                L1 += k1; L2 += k2; L3 += k3; L4 += k4;
                M0 += vv;
                M1 = fmaf(k1, vv, M1);
                M2 = fmaf(k2, vv, M2);
                M3 = fmaf(k3, vv, M3);
                M4 = fmaf(k4, vv, M4);
            }
        #pragma unroll
        for (int m = 16; m <= 32; m <<= 1) {
            L1 += __shfl_xor(L1, m); L2 += __shfl_xor(L2, m);
            L3 += __shfl_xor(L3, m); L4 += __shfl_xor(L4, m);
            M0 += __shfl_xor(M0, m); M1 += __shfl_xor(M1, m);
            M2 += __shfl_xor(M2, m); M3 += __shfl_xor(M3, m);
            M4 += __shfl_xor(M4, m);
        }
        const float a4 = L4 * (1.f / 24.f), a3 = L3 * (1.f / 6.f), a2 = L2 * 0.5f;
        const float b4 = M4 * (1.f / 24.f), b3 = M3 * (1.f / 6.f), b2 = M2 * 0.5f;

        // XFo A-frag coords for feature f: kt2 = wv>>1, g2 = (wv&1)*2+(ln16>>3),
        // jj = ln16&7  (f = kt2*32 + g2*8 + jj).
        const int kt2 = wv >> 1;
        const int g2  = (wv & 1) * 2 + (ln16 >> 3);
        const int jj  = ln16 & 7;
        #pragma unroll
        for (int mt = 0; mt < 4; ++mt)
            #pragma unroll
            for (int r = 0; r < 4; ++r) {
                const float qv = acc[mt][0][r];
                const float gv = __builtin_amdgcn_rcpf(
                    1.f + __builtin_amdgcn_exp2f(acc[mt][3][r] * -1.44269504f));
                const float den = fmaf(fmaf(fmaf(fmaf(a4, qv, a3), qv, a2), qv, L1), qv, 64.f);
                const float num = fmaf(fmaf(fmaf(fmaf(b4, qv, b3), qv, b2), qv, M1), qv, M0);
                const float o   = gv * num * __builtin_amdgcn_rcpf(den);
                XFo[((kt2 * 4 + mt) * 64 + g2 * 16 + lg * 4 + r) * 8 + jj] = f2bf(o);
            }
    }

    // pack Wout frags (loads landed during attention)
    bf16x8 ofr[8];
    #pragma unroll
    for (int kt = 0; kt < 8; ++kt) ofr[kt] = pack8(wo[kt]);
    __syncthreads();

    // ---------------- out-proj (K=256) -> direct store + bias ----------------
    // wave -> (mt4 s-block, nn2 c-tile of 16). 8 kt MFMAs.
    {
        f32x4 a2v = (f32x4){0.f, 0.f, 0.f, 0.f};
        #pragma unroll
        for (int kt = 0; kt < 8; ++kt) {
            const bf16x8 afr = *(const bf16x8*)(XFo + ((kt * 4 + mt4) * 64 + l) * 8);
            a2v = __builtin_amdgcn_mfma_f32_16x16x32_bf16(afr, ofr[kt], a2v, 0, 0, 0);
        }
        const float bb = bout[cc];
        #pragma unroll
        for (int r = 0; r < 4; ++r) {
            const int s = mt4 * 16 + lg * 4 + r;
            out[(s * 128 + i) * 64 + cc] = a2v[r] + bb;
        }
    }
}

extern "C" void kernel_launch(void* const* d_in, const int* in_sizes, int n_in,
                              void* d_out, int out_size, void* d_ws, size_t ws_size,
                              hipStream_t stream) {
    (void)in_sizes; (void)n_in; (void)d_ws; (void)ws_size; (void)out_size;
    const float* msa  = (const float*)d_in[0];
    const float* ln_s = (const float*)d_in[1];
    const float* ln_b = (const float*)d_in[2];
    const float* Wqkv = (const float*)d_in[3];
    const float* Wg   = (const float*)d_in[4];
    const float* Wout = (const float*)d_in[5];
    const float* bout = (const float*)d_in[6];
    float* out = (float*)d_out;

    msa_col_attn_fused<<<dim3(128), dim3(1024), 0, stream>>>(
        msa, ln_s, ln_b, Wqkv, Wg, Wout, bout, out);
}